// Round 8
// baseline (679.393 us; speedup 1.0000x reference)
//
#include <hip/hip_runtime.h>
#include <hip/hip_bf16.h>

#define T_TOK 4096
#define H_DIM 1024
#define E_EXP 64
#define TOPK  8
#define F_DIM 512
#define CAP   1024
#define A_TOT (T_TOK * TOPK)   // 32768

typedef _Float16 f16;
typedef _Float16 f16x4 __attribute__((ext_vector_type(4)));
typedef _Float16 f16x8 __attribute__((ext_vector_type(8)));
typedef float    f32x4 __attribute__((ext_vector_type(4)));

// ---------------------------------------------------------------------------
// K0 v7: sequential reads AND sequential writes. v3-v6 all pinned ~150us /
// ~2.6 TB/s with 4 different READ patterns -> reads exonerated; the shared
// trait was 1KB-scattered WRITES (chunk stride kb*1KB for fixed kt). v7
// reorders the packed layout to [e][kt][nt]: block (e,kt) writes its 32
// chunks as ONE contiguous 32KB run. Read side = v6 (64KB linear slab ->
// LDS transpose). Gemms updated to the new chunk order.
// Blocks: w1 [0,2048), w3 [2048,4096), w2 [4096,6144).
// ---------------------------------------------------------------------------
__global__ __launch_bounds__(256) void pack_all_kernel(
    const float* __restrict__ w1, const float* __restrict__ w3,
    const float* __restrict__ w2,
    f16* __restrict__ w1p, f16* __restrict__ w3p, f16* __restrict__ w2p)
{
    __shared__ f16 Ls[32][516];
    const int tid = threadIdx.x;
    const int bid = blockIdx.x;
    const float* src; f16* dst; int Nd, kb, ntb, e, kt, ch;
    if (bid < 2048)      { src = w1; dst = w1p; Nd = 512;  kb = 32; ntb = 32; e = bid >> 5;          kt = bid & 31;          ch = 0; }
    else if (bid < 4096) { src = w3; dst = w3p; Nd = 512;  kb = 32; ntb = 32; e = (bid - 2048) >> 5; kt = (bid - 2048) & 31; ch = 0; }
    else { src = w2; dst = w2p; Nd = 1024; kb = 16; ntb = 64; int r = bid - 4096; e = r >> 5; kt = (r >> 1) & 15; ch = r & 1; }
    const int Kd = kb << 5;

    const float* base = src + ((size_t)e * Kd + kt * 32) * Nd + ch * 512;
    #pragma unroll
    for (int p = 0; p < 16; ++p) {
        int idx = p * 256 + tid;
        int row = idx >> 7, c4 = (idx & 127) * 4;   // 128 float4 per 512-col row
        float4 v = *(const float4*)(base + (size_t)row * Nd + c4);
        f16x4 hv;
        hv[0] = (f16)v.x; hv[1] = (f16)v.y; hv[2] = (f16)v.z; hv[3] = (f16)v.w;
        *(f16x4*)&Ls[row][c4] = hv;
    }
    __syncthreads();
    const int lane = tid & 63, wvi = tid >> 6;
    const int jj = lane & 15, qq = lane >> 4;
    #pragma unroll
    for (int i = 0; i < 8; ++i) {
        int ntl = wvi * 8 + i;                      // local n-tile within this 512-col chunk
        f16x8 o;
        #pragma unroll
        for (int j = 0; j < 8; ++j)
            o[j] = Ls[qq * 8 + j][ntl * 16 + jj];
        // NEW layout: chunk(e,kt,nt) = (e*kb + kt)*ntb + nt  -> block-contiguous
        size_t chunk = ((size_t)e * kb + kt) * ntb + (ch * 32 + ntl);
        *(f16x8*)(dst + chunk * 512 + lane * 8) = o;
    }
}

// ---------------------------------------------------------------------------
// K1: router — fp32 logits, top-8 (stable), renormalized weights; emits fp16 x.
// ---------------------------------------------------------------------------
__global__ __launch_bounds__(256) void router_kernel(
    const float* __restrict__ x, const float* __restrict__ wg,
    float* __restrict__ logits_out, int* __restrict__ sel,
    float* __restrict__ wgtA, f16* __restrict__ xh)
{
    __shared__ float xs[16][128];
    __shared__ float ls[16][65];
    const int tid = threadIdx.x;
    const int e  = tid & 63;
    const int tg = tid >> 6;
    const int tb = blockIdx.x * 16;

    float acc[4] = {0.f, 0.f, 0.f, 0.f};
    for (int h0 = 0; h0 < H_DIM; h0 += 128) {
        {
            int r  = tid >> 4;
            int c0 = (tid & 15) * 8;
            const float4* src = (const float4*)(x + (size_t)(tb + r) * H_DIM + h0 + c0);
            float4 v0 = src[0], v1 = src[1];
            *(float4*)&xs[r][c0]     = v0;
            *(float4*)&xs[r][c0 + 4] = v1;
            f16x8 hv;
            hv[0] = (f16)v0.x; hv[1] = (f16)v0.y; hv[2] = (f16)v0.z; hv[3] = (f16)v0.w;
            hv[4] = (f16)v1.x; hv[5] = (f16)v1.y; hv[6] = (f16)v1.z; hv[7] = (f16)v1.w;
            *(f16x8*)(xh + (size_t)(tb + r) * H_DIM + h0 + c0) = hv;
        }
        __syncthreads();
        for (int hh = 0; hh < 128; ++hh) {
            float w = wg[(size_t)(h0 + hh) * E_EXP + e];
            #pragma unroll
            for (int i = 0; i < 4; ++i)
                acc[i] = fmaf(xs[tg * 4 + i][hh], w, acc[i]);
        }
        __syncthreads();
    }
    #pragma unroll
    for (int i = 0; i < 4; ++i) {
        int tt = tg * 4 + i;
        logits_out[(size_t)(tb + tt) * E_EXP + e] = acc[i];
        ls[tt][e] = acc[i];
    }
    __syncthreads();
    if (tid < 16) {
        int tt = tid;
        float lv[8]; int li[8];
        for (int k = 0; k < 8; ++k) {
            float m = -1e30f; int mi = 0;
            for (int j = 0; j < 64; ++j) {
                float v = ls[tt][j];
                if (v > m) { m = v; mi = j; }   // strict > : lowest index wins (stable)
            }
            lv[k] = m; li[k] = mi;
            ls[tt][mi] = -1e30f;
        }
        float s = 0.f, wv[8];
        for (int k = 0; k < 8; ++k) { wv[k] = __expf(lv[k] - lv[0]); s += wv[k]; }
        float inv = 1.f / s;
        for (int k = 0; k < 8; ++k) {
            int a = (tb + tt) * TOPK + k;
            sel[a]  = li[k];
            wgtA[a] = wv[k] * inv;
        }
    }
}

// ---------------------------------------------------------------------------
// K2: per-expert stable token lists + capacity drop (matches argsort(stable)).
// Also emits the inverse map slotA[a] = e*CAP+pos (-1 if dropped) for combine.
// ---------------------------------------------------------------------------
__global__ __launch_bounds__(256) void build_lists_kernel(
    const int* __restrict__ sel,
    int* __restrict__ tok_list, int* __restrict__ slotA,
    int* __restrict__ counts)
{
    __shared__ int sc[256];
    const int e = blockIdx.x;
    const int tid = threadIdx.x;
    const int per = A_TOT / 256;
    const int a0 = tid * per;
    int cnt = 0;
    for (int i = 0; i < per; ++i) cnt += (sel[a0 + i] == e) ? 1 : 0;
    sc[tid] = cnt;
    __syncthreads();
    for (int s = 1; s < 256; s <<= 1) {
        int v = (tid >= s) ? sc[tid - s] : 0;
        __syncthreads();
        sc[tid] += v;
        __syncthreads();
    }
    int total = sc[255];
    int pos = sc[tid] - cnt;
    if (tid == 0) counts[e] = (total < CAP) ? total : CAP;
    for (int i = 0; i < per; ++i) {
        int a = a0 + i;
        if (sel[a] == e) {
            if (pos < CAP) {
                tok_list[e * CAP + pos] = a >> 3;
                slotA[a] = e * CAP + pos;
            } else {
                slotA[a] = -1;                  // dropped (never happens at CAP_FACTOR=2)
            }
            pos++;
        }
    }
}

#define MFMA16(a, b, c) __builtin_amdgcn_mfma_f32_16x16x32_f16(a, b, c, 0, 0, 0)

// ---------------------------------------------------------------------------
// K3a v6: R1 geometry + verified swizzle + NEW [e][kt][nt] weight order +
// LDS-staged epilogue (scalar 2B P-stores -> f16x8 128B-row-segment stores).
// ---------------------------------------------------------------------------
__global__ __launch_bounds__(256) void gemm1_kernel(
    const f16* __restrict__ xh, const f16* __restrict__ w1p,
    const f16* __restrict__ w3p, const int* __restrict__ tok_list,
    const int* __restrict__ counts, f16* __restrict__ P)
{
    const int id = blockIdx.x;
    const int x7 = id & 7, r = id >> 3;
    const int ft = r & 7, mt = (r >> 3) & 15, eh = r >> 7;
    const int e = x7 + 8 * eh;
    const int cnt = counts[e];
    const int m0 = mt * 64;
    if (m0 >= cnt) return;
    const int bf = ft * 64;

    __shared__ f16 Xs[2][64][64];
    __shared__ int tok_s[64];

    const int tid = threadIdx.x;
    const int lane = tid & 63, wv = tid >> 6;
    const int jj = lane & 15, qq = lane >> 4;
    const int sr = tid >> 3, sc = (tid & 7) * 8;
    const int swz_w = ((tid & 7) ^ (sr & 7)) * 8;     // swizzled write slot
    const int x8 = jj & 7;
    const int s0 = (qq ^ x8) * 8;                     // swizzled read slot, k-half 0
    const int s1 = ((qq + 4) ^ x8) * 8;               // swizzled read slot, k-half 1

    if (tid < 64) {
        int m = m0 + tid;
        tok_s[tid] = (m < cnt) ? tok_list[e * CAP + m] : tok_list[e * CAP];
    }
    __syncthreads();
    const size_t rowA = (size_t)tok_s[sr] * H_DIM + sc;
    const size_t rowB = (size_t)tok_s[sr + 32] * H_DIM + sc;

    const int nt = ft * 4 + wv;                       // one 16-col n-tile per wave
    // [e][kt][nt] order: chunk = (e*32 + kt)*32 + nt; k-half stride 32*512
    const f16* w1a = w1p + ((size_t)(e * 32) * 32 + nt) * 512 + lane * 8;
    const f16* w3a = w3p + ((size_t)(e * 32) * 32 + nt) * 512 + lane * 8;
    const size_t KH = (size_t)32 * 512;               // k-half (kt) stride

    f32x4 accG[4], accU[4];
    #pragma unroll
    for (int i = 0; i < 4; ++i) {
        accG[i] = (f32x4){0.f, 0.f, 0.f, 0.f};
        accU[i] = (f32x4){0.f, 0.f, 0.f, 0.f};
    }

    // prologue: stage k-block 0 + first weight frags
    {
        f16x8 a = *(const f16x8*)(xh + rowA);
        f16x8 b = *(const f16x8*)(xh + rowB);
        *(f16x8*)&Xs[0][sr][swz_w]      = a;
        *(f16x8*)&Xs[0][sr + 32][swz_w] = b;
    }
    f16x8 cG0 = *(const f16x8*)(w1a);
    f16x8 cG1 = *(const f16x8*)(w1a + KH);
    f16x8 cU0 = *(const f16x8*)(w3a);
    f16x8 cU1 = *(const f16x8*)(w3a + KH);

    #pragma unroll
    for (int it = 0; it < 16; ++it) {
        const int k0 = it * 64;
        __syncthreads();                       // Xs[it&1] visible; prior readers of Xs[(it+1)&1] done
        f16x8 xn0, xn1, nG0, nG1, nU0, nU1;
        if (it < 15) {                         // issue next-iter loads before MFMAs
            xn0 = *(const f16x8*)(xh + rowA + k0 + 64);
            xn1 = *(const f16x8*)(xh + rowB + k0 + 64);
            size_t kg = (size_t)(2 * it + 2) * KH;
            nG0 = *(const f16x8*)(w1a + kg);
            nG1 = *(const f16x8*)(w1a + kg + KH);
            nU0 = *(const f16x8*)(w3a + kg);
            nU1 = *(const f16x8*)(w3a + kg + KH);
        }
        const int buf = it & 1;
        #pragma unroll
        for (int m2 = 0; m2 < 4; ++m2) {
            f16x8 a0 = *(const f16x8*)&Xs[buf][m2 * 16 + jj][s0];
            f16x8 a1 = *(const f16x8*)&Xs[buf][m2 * 16 + jj][s1];
            accG[m2] = MFMA16(a0, cG0, accG[m2]);
            accU[m2] = MFMA16(a0, cU0, accU[m2]);
            accG[m2] = MFMA16(a1, cG1, accG[m2]);
            accU[m2] = MFMA16(a1, cU1, accU[m2]);
        }
        if (it < 15) {
            *(f16x8*)&Xs[buf ^ 1][sr][swz_w]      = xn0;
            *(f16x8*)&Xs[buf ^ 1][sr + 32][swz_w] = xn1;
            cG0 = nG0; cG1 = nG1; cU0 = nU0; cU1 = nU1;
        }
    }
    // LDS-staged epilogue: silu*up -> Ct (overlays Xs) -> coalesced 128B rows
    __syncthreads();
    f16 (*Ct)[72] = (f16(*)[72])Xs;           // 64x72 f16 = 9216B < 16KB
    #pragma unroll
    for (int m2 = 0; m2 < 4; ++m2) {
        #pragma unroll
        for (int rr = 0; rr < 4; ++rr) {
            int row = m2 * 16 + qq * 4 + rr;
            float gg = accG[m2][rr], u = accU[m2][rr];
            float p = gg / (1.f + __expf(-gg)) * u;
            Ct[row][wv * 16 + jj] = (f16)p;
        }
    }
    __syncthreads();
    #pragma unroll
    for (int i = 0; i < 2; ++i) {
        int row = (tid >> 3) + i * 32;
        int col = (tid & 7) * 8;
        f16x8 v = *(f16x8*)&Ct[row][col];
        *(f16x8*)(P + (size_t)(e * CAP + m0 + row) * F_DIM + bf + col) = v;
    }
}

// ---------------------------------------------------------------------------
// K3b v6: R1 geometry + verified swizzle + NEW [e][kt][nt] weight order +
// LDS-staged epilogue (scalar 2B Y-stores -> f16x8 256B-row-segment stores).
// ---------------------------------------------------------------------------
__global__ __launch_bounds__(256) void gemm2_kernel(
    const f16* __restrict__ P, const f16* __restrict__ w2p,
    const int* __restrict__ counts, f16* __restrict__ Y)
{
    const int id = blockIdx.x;
    const int x7 = id & 7, r = id >> 3;
    const int ht = r & 7, mt = (r >> 3) & 15, eh = r >> 7;
    const int e = x7 + 8 * eh;
    const int cnt = counts[e];
    const int m0 = mt * 64;
    if (m0 >= cnt) return;
    const int h0 = ht * 128;

    __shared__ f16 Ps[2][64][64];

    const int tid = threadIdx.x;
    const int lane = tid & 63, wv = tid >> 6;
    const int jj = lane & 15, qq = lane >> 4;
    const int sr = tid >> 3, sc = (tid & 7) * 8;
    const int swz_w = ((tid & 7) ^ (sr & 7)) * 8;
    const int x8 = jj & 7;
    const int s0 = (qq ^ x8) * 8;
    const int s1 = ((qq + 4) ^ x8) * 8;

    const size_t pbase = (size_t)(e * CAP + m0) * F_DIM;
    // [e][kt][nt] order: chunk = (e*16 + kt)*64 + nt; k-half stride 64*512
    const size_t KH = (size_t)64 * 512;
    const f16* wA = w2p + ((size_t)(e * 16) * 64 + ht * 8 + wv) * 512 + lane * 8;
    const f16* wB = wA + (size_t)4 * 512;

    f32x4 accA[4], accB[4];
    #pragma unroll
    for (int i = 0; i < 4; ++i) {
        accA[i] = (f32x4){0.f, 0.f, 0.f, 0.f};
        accB[i] = (f32x4){0.f, 0.f, 0.f, 0.f};
    }

    {
        f16x8 a = *(const f16x8*)(P + pbase + (size_t)sr * F_DIM + sc);
        f16x8 b = *(const f16x8*)(P + pbase + (size_t)(sr + 32) * F_DIM + sc);
        *(f16x8*)&Ps[0][sr][swz_w]      = a;
        *(f16x8*)&Ps[0][sr + 32][swz_w] = b;
    }
    f16x8 cA0 = *(const f16x8*)(wA);
    f16x8 cA1 = *(const f16x8*)(wA + KH);
    f16x8 cB0 = *(const f16x8*)(wB);
    f16x8 cB1 = *(const f16x8*)(wB + KH);

    #pragma unroll
    for (int it = 0; it < 8; ++it) {
        const int k0 = it * 64;
        __syncthreads();
        f16x8 pn0, pn1, nA0, nA1, nB0, nB1;
        if (it < 7) {
            pn0 = *(const f16x8*)(P + pbase + (size_t)sr * F_DIM + k0 + 64 + sc);
            pn1 = *(const f16x8*)(P + pbase + (size_t)(sr + 32) * F_DIM + k0 + 64 + sc);
            size_t kg = (size_t)(2 * it + 2) * KH;
            nA0 = *(const f16x8*)(wA + kg);
            nA1 = *(const f16x8*)(wA + kg + KH);
            nB0 = *(const f16x8*)(wB + kg);
            nB1 = *(const f16x8*)(wB + kg + KH);
        }
        const int buf = it & 1;
        #pragma unroll
        for (int m2 = 0; m2 < 4; ++m2) {
            f16x8 a0 = *(const f16x8*)&Ps[buf][m2 * 16 + jj][s0];
            f16x8 a1 = *(const f16x8*)&Ps[buf][m2 * 16 + jj][s1];
            accA[m2] = MFMA16(a0, cA0, accA[m2]);
            accB[m2] = MFMA16(a0, cB0, accB[m2]);
            accA[m2] = MFMA16(a1, cA1, accA[m2]);
            accB[m2] = MFMA16(a1, cB1, accB[m2]);
        }
        if (it < 7) {
            *(f16x8*)&Ps[buf ^ 1][sr][swz_w]      = pn0;
            *(f16x8*)&Ps[buf ^ 1][sr + 32][swz_w] = pn1;
            cA0 = nA0; cA1 = nA1; cB0 = nB0; cB1 = nB1;
        }
    }
    // LDS-staged epilogue: acc -> Ct2 (overlays Ps, 16KB) -> coalesced 256B rows
    __syncthreads();
    f16 (*Ct2)[128] = (f16(*)[128])Ps;        // 64x128 f16 = 16KB
    #pragma unroll
    for (int m2 = 0; m2 < 4; ++m2) {
        #pragma unroll
        for (int rr = 0; rr < 4; ++rr) {
            int row = m2 * 16 + qq * 4 + rr;
            Ct2[row][wv * 16 + jj]      = (f16)accA[m2][rr];
            Ct2[row][wv * 16 + jj + 64] = (f16)accB[m2][rr];
        }
    }
    __syncthreads();
    #pragma unroll
    for (int i = 0; i < 4; ++i) {
        int row = (tid >> 4) + i * 16;
        int col = (tid & 15) * 8;
        f16x8 v = *(f16x8*)&Ct2[row][col];
        *(f16x8*)(Y + (size_t)(e * CAP + m0 + row) * H_DIM + h0 + col) = v;
    }
}

// ---------------------------------------------------------------------------
// K4: combine — out[t] = sum_k wgt[t,k] * Y[slot[t,k]]. Streaming gather;
// fully overwrites out (no memset needed). 2 tokens/block, 128 thr/token.
// ---------------------------------------------------------------------------
__global__ __launch_bounds__(256) void combine_kernel(
    const f16* __restrict__ Y, const int* __restrict__ slotA,
    const float* __restrict__ wgtA, float* __restrict__ out)
{
    const int tid = threadIdx.x;
    const int t  = blockIdx.x * 2 + (tid >> 7);
    const int hc = (tid & 127) * 8;
    float acc[8] = {0.f, 0.f, 0.f, 0.f, 0.f, 0.f, 0.f, 0.f};
    const int base = t * TOPK;
    #pragma unroll
    for (int k = 0; k < 8; ++k) {
        int s   = slotA[base + k];      // wave-uniform
        float w = wgtA[base + k];
        if (s >= 0) {
            f16x8 y = *(const f16x8*)(Y + (size_t)s * H_DIM + hc);
            #pragma unroll
            for (int j = 0; j < 8; ++j) acc[j] += w * (float)y[j];
        }
    }
    float4 o0 = {acc[0], acc[1], acc[2], acc[3]};
    float4 o1 = {acc[4], acc[5], acc[6], acc[7]};
    *(float4*)(out + (size_t)t * H_DIM + hc)     = o0;
    *(float4*)(out + (size_t)t * H_DIM + hc + 4) = o1;
}

extern "C" void kernel_launch(void* const* d_in, const int* in_sizes, int n_in,
                              void* d_out, int out_size, void* d_ws, size_t ws_size,
                              hipStream_t stream) {
    const float* x  = (const float*)d_in[0];   // [T,H]
    const float* wg = (const float*)d_in[1];   // [H,E]
    const float* w1 = (const float*)d_in[2];   // [E,H,F]
    const float* w3 = (const float*)d_in[3];   // [E,H,F]
    const float* w2 = (const float*)d_in[4];   // [E,F,H]

    float* out    = (float*)d_out;
    float* logits = out + (size_t)T_TOK * H_DIM;

    char* ws = (char*)d_ws;
    int*   sel      = (int*)  (ws);
    float* wgtA     = (float*)(ws + (128 << 10));
    int*   tok_list = (int*)  (ws + (256 << 10));
    int*   slotA    = (int*)  (ws + (512 << 10));
    int*   counts   = (int*)  (ws + (768 << 10));
    f16*   xh       = (f16*)  (ws + (size_t)(1 << 20));     // 8 MB
    f16*   P        = (f16*)  (ws + (size_t)(9 << 20));     // 64 MB
    f16*   w1p      = (f16*)  (ws + (size_t)(73 << 20));    // 64 MB
    f16*   w3p      = (f16*)  (ws + (size_t)(137 << 20));   // 64 MB
    f16*   w2p      = (f16*)  (ws + (size_t)(201 << 20));   // 64 MB (end 265 MB)
    // Y aliases w1p+w3p (dead after gemm1; same-stream ordering makes this safe)
    f16*   Y        = (f16*)  (ws + (size_t)(73 << 20));    // 128 MB [E*CAP, H]

    pack_all_kernel<<<6144, 256, 0, stream>>>(w1, w3, w2, w1p, w3p, w2p);
    router_kernel<<<T_TOK / 16, 256, 0, stream>>>(x, wg, logits, sel, wgtA, xh);
    build_lists_kernel<<<E_EXP, 256, 0, stream>>>(sel, tok_list, slotA, counts);
    gemm1_kernel<<<8192, 256, 0, stream>>>(xh, w1p, w3p, tok_list, counts, P);
    gemm2_kernel<<<8192, 256, 0, stream>>>(P, w2p, counts, Y);
    combine_kernel<<<T_TOK / 2, 256, 0, stream>>>(Y, slotA, wgtA, out);
}

// Round 9
// 640.607 us; speedup vs baseline: 1.0605x; 1.0605x over previous
//
#include <hip/hip_runtime.h>
#include <hip/hip_bf16.h>

#define T_TOK 4096
#define H_DIM 1024
#define E_EXP 64
#define TOPK  8
#define F_DIM 512
#define CAP   1024
#define A_TOT (T_TOK * TOPK)   // 32768

typedef _Float16 f16;
typedef _Float16 f16x4 __attribute__((ext_vector_type(4)));
typedef _Float16 f16x8 __attribute__((ext_vector_type(8)));
typedef float    f32x4 __attribute__((ext_vector_type(4)));

// ---------------------------------------------------------------------------
// K0 (R4's proven v4, split per-matrix for profile visibility): fp32
// [E][Kd][Nd] -> f16 B-fragment chunks [e][nt][kt] of 512 f16. Each wave
// packs an adjacent n-tile pair (full 128B line per quarter-wave row read).
// Split into 3 launches so each (~50us) sits BELOW the gemms in the top-5.
// Pack is pinned at ~3.5 TB/s combined across 5 structural variants -> not
// iterating further; this is the measured-best version (R4, 655us total).
// ---------------------------------------------------------------------------
__global__ __launch_bounds__(256) void pack_w_kernel(
    const float* __restrict__ src, f16* __restrict__ dst,
    int Nd, int kb, int kbs, int nps)
{
    const int tid  = threadIdx.x;
    const int lane = tid & 63, wvi = tid >> 6;
    const int pid = blockIdx.x * 4 + wvi;
    const int kt  = pid & (kb - 1);
    const int en  = pid >> kbs;
    const int ntp = en & ((1 << nps) - 1);    // n-tile-pair index
    const int e   = en >> nps;
    const int Kd  = kb << 5;
    const int jj = lane & 15, qq = lane >> 4;
    const float* s = src + ((size_t)e * Kd + kt * 32 + qq * 8) * Nd + ntp * 32 + jj;
    f16x8 v0, v1;
    #pragma unroll
    for (int j = 0; j < 8; ++j) {
        float a = s[(size_t)j * Nd];
        float b = s[(size_t)j * Nd + 16];
        v0[j] = (f16)a;
        v1[j] = (f16)b;
    }
    size_t c0 = (size_t)(e * (Nd >> 4) + ntp * 2) * kb + kt;   // [e][nt][kt]
    *(f16x8*)(dst + c0 * 512 + lane * 8)        = v0;
    *(f16x8*)(dst + (c0 + kb) * 512 + lane * 8) = v1;   // nt+1 is kb chunks later
}

// ---------------------------------------------------------------------------
// K1 v2: parallel router. Old router: 256 blocks = 1 block/CU = 4 waves/CU,
// 1024-deep serial FMA chain, in-loop global loads, 16 barriers -> latency-
// bound (prime suspect for the ~250us unattributed time). New: 1024 blocks,
// thread = (token tt=tid>>6, expert e=tid&63); x staged once in LDS (wave-
// uniform broadcast reads); wg reads coalesced 256B, L2-resident; 2-chain
// ILP. Same verified stable top-8 + renorm code (strict >, lowest index).
// ---------------------------------------------------------------------------
__global__ __launch_bounds__(256) void router_kernel(
    const float* __restrict__ x, const float* __restrict__ wg,
    float* __restrict__ logits_out, int* __restrict__ sel,
    float* __restrict__ wgtA, f16* __restrict__ xh)
{
    __shared__ float xs[4][1024];
    __shared__ float ls[4][65];
    const int tid = threadIdx.x;
    const int tt = tid >> 6;          // token within block
    const int e  = tid & 63;
    const int tb = blockIdx.x * 4;

    #pragma unroll
    for (int i = 0; i < 4; ++i) {
        int idx = i * 256 + tid;                  // 0..1023
        int r = idx >> 8, c4 = (idx & 255) * 4;
        float4 v = *(const float4*)(x + (size_t)(tb + r) * H_DIM + c4);
        *(float4*)&xs[r][c4] = v;
        f16x4 hv;
        hv[0] = (f16)v.x; hv[1] = (f16)v.y; hv[2] = (f16)v.z; hv[3] = (f16)v.w;
        *(f16x4*)(xh + (size_t)(tb + r) * H_DIM + c4) = hv;
    }
    __syncthreads();

    float a0 = 0.f, a1 = 0.f;
    #pragma unroll 8
    for (int h = 0; h < H_DIM; h += 2) {
        a0 = fmaf(xs[tt][h],     wg[(size_t)h * E_EXP + e],       a0);
        a1 = fmaf(xs[tt][h + 1], wg[(size_t)(h + 1) * E_EXP + e], a1);
    }
    float acc = a0 + a1;
    logits_out[(size_t)(tb + tt) * E_EXP + e] = acc;
    ls[tt][e] = acc;
    __syncthreads();

    if (tid < 4) {
        int t4 = tid;
        float lv[8]; int li[8];
        for (int k = 0; k < 8; ++k) {
            float m = -1e30f; int mi = 0;
            for (int j = 0; j < 64; ++j) {
                float v = ls[t4][j];
                if (v > m) { m = v; mi = j; }   // strict > : lowest index wins (stable)
            }
            lv[k] = m; li[k] = mi;
            ls[t4][mi] = -1e30f;
        }
        float s = 0.f, wv[8];
        for (int k = 0; k < 8; ++k) { wv[k] = __expf(lv[k] - lv[0]); s += wv[k]; }
        float inv = 1.f / s;
        for (int k = 0; k < 8; ++k) {
            int a = (tb + t4) * TOPK + k;
            sel[a]  = li[k];
            wgtA[a] = wv[k] * inv;
        }
    }
}

// ---------------------------------------------------------------------------
// K2: per-expert stable token lists + capacity drop (matches argsort(stable)).
// Also emits the inverse map slotA[a] = e*CAP+pos (-1 if dropped) for combine.
// ---------------------------------------------------------------------------
__global__ __launch_bounds__(256) void build_lists_kernel(
    const int* __restrict__ sel,
    int* __restrict__ tok_list, int* __restrict__ slotA,
    int* __restrict__ counts)
{
    __shared__ int sc[256];
    const int e = blockIdx.x;
    const int tid = threadIdx.x;
    const int per = A_TOT / 256;
    const int a0 = tid * per;
    int cnt = 0;
    for (int i = 0; i < per; ++i) cnt += (sel[a0 + i] == e) ? 1 : 0;
    sc[tid] = cnt;
    __syncthreads();
    for (int s = 1; s < 256; s <<= 1) {
        int v = (tid >= s) ? sc[tid - s] : 0;
        __syncthreads();
        sc[tid] += v;
        __syncthreads();
    }
    int total = sc[255];
    int pos = sc[tid] - cnt;
    if (tid == 0) counts[e] = (total < CAP) ? total : CAP;
    for (int i = 0; i < per; ++i) {
        int a = a0 + i;
        if (sel[a] == e) {
            if (pos < CAP) {
                tok_list[e * CAP + pos] = a >> 3;
                slotA[a] = e * CAP + pos;
            } else {
                slotA[a] = -1;                  // dropped (never happens at CAP_FACTOR=2)
            }
            pos++;
        }
    }
}

#define MFMA16(a, b, c) __builtin_amdgcn_mfma_f32_16x16x32_f16(a, b, c, 0, 0, 0)

// ---------------------------------------------------------------------------
// K3a (R4 exact): R1 geometry (64 rows x 64 F-cols, 256 thr, 8192 blocks,
// VGPR ~64, occ ~39%) + verified XOR swizzle on unpadded Xs[64][64]
// (SQ_LDS_BANK_CONFLICT 8.9M -> 0). [e][nt][kt] weight order.
// ---------------------------------------------------------------------------
__global__ __launch_bounds__(256) void gemm1_kernel(
    const f16* __restrict__ xh, const f16* __restrict__ w1p,
    const f16* __restrict__ w3p, const int* __restrict__ tok_list,
    const int* __restrict__ counts, f16* __restrict__ P)
{
    const int id = blockIdx.x;
    const int x7 = id & 7, r = id >> 3;
    const int ft = r & 7, mt = (r >> 3) & 15, eh = r >> 7;
    const int e = x7 + 8 * eh;
    const int cnt = counts[e];
    const int m0 = mt * 64;
    if (m0 >= cnt) return;
    const int bf = ft * 64;

    __shared__ f16 Xs[2][64][64];
    __shared__ int tok_s[64];

    const int tid = threadIdx.x;
    const int lane = tid & 63, wv = tid >> 6;
    const int jj = lane & 15, qq = lane >> 4;
    const int sr = tid >> 3, sc = (tid & 7) * 8;
    const int swz_w = ((tid & 7) ^ (sr & 7)) * 8;     // swizzled write slot
    const int x8 = jj & 7;
    const int s0 = (qq ^ x8) * 8;                     // swizzled read slot, k-half 0
    const int s1 = ((qq + 4) ^ x8) * 8;               // swizzled read slot, k-half 1

    if (tid < 64) {
        int m = m0 + tid;
        tok_s[tid] = (m < cnt) ? tok_list[e * CAP + m] : tok_list[e * CAP];
    }
    __syncthreads();
    const size_t rowA = (size_t)tok_s[sr] * H_DIM + sc;
    const size_t rowB = (size_t)tok_s[sr + 32] * H_DIM + sc;

    const int nt = ft * 4 + wv;                       // one 16-col n-tile per wave
    const f16* w1a = w1p + ((size_t)(e * 32 + nt) * 32) * 512 + lane * 8;
    const f16* w3a = w3p + ((size_t)(e * 32 + nt) * 32) * 512 + lane * 8;

    f32x4 accG[4], accU[4];
    #pragma unroll
    for (int i = 0; i < 4; ++i) {
        accG[i] = (f32x4){0.f, 0.f, 0.f, 0.f};
        accU[i] = (f32x4){0.f, 0.f, 0.f, 0.f};
    }

    // prologue: stage k-block 0 + first weight frags
    {
        f16x8 a = *(const f16x8*)(xh + rowA);
        f16x8 b = *(const f16x8*)(xh + rowB);
        *(f16x8*)&Xs[0][sr][swz_w]      = a;
        *(f16x8*)&Xs[0][sr + 32][swz_w] = b;
    }
    f16x8 cG0 = *(const f16x8*)(w1a);
    f16x8 cG1 = *(const f16x8*)(w1a + 512);
    f16x8 cU0 = *(const f16x8*)(w3a);
    f16x8 cU1 = *(const f16x8*)(w3a + 512);

    #pragma unroll
    for (int it = 0; it < 16; ++it) {
        const int k0 = it * 64;
        __syncthreads();                       // Xs[it&1] visible; prior readers of Xs[(it+1)&1] done
        f16x8 xn0, xn1, nG0, nG1, nU0, nU1;
        if (it < 15) {                         // issue next-iter loads before MFMAs
            xn0 = *(const f16x8*)(xh + rowA + k0 + 64);
            xn1 = *(const f16x8*)(xh + rowB + k0 + 64);
            size_t kg = (size_t)(2 * it + 2) * 512;
            nG0 = *(const f16x8*)(w1a + kg);
            nG1 = *(const f16x8*)(w1a + kg + 512);
            nU0 = *(const f16x8*)(w3a + kg);
            nU1 = *(const f16x8*)(w3a + kg + 512);
        }
        const int buf = it & 1;
        #pragma unroll
        for (int m2 = 0; m2 < 4; ++m2) {
            f16x8 a0 = *(const f16x8*)&Xs[buf][m2 * 16 + jj][s0];
            f16x8 a1 = *(const f16x8*)&Xs[buf][m2 * 16 + jj][s1];
            accG[m2] = MFMA16(a0, cG0, accG[m2]);
            accU[m2] = MFMA16(a0, cU0, accU[m2]);
            accG[m2] = MFMA16(a1, cG1, accG[m2]);
            accU[m2] = MFMA16(a1, cU1, accU[m2]);
        }
        if (it < 15) {
            *(f16x8*)&Xs[buf ^ 1][sr][swz_w]      = xn0;
            *(f16x8*)&Xs[buf ^ 1][sr + 32][swz_w] = xn1;
            cG0 = nG0; cG1 = nG1; cU0 = nU0; cU1 = nU1;
        }
    }
    #pragma unroll
    for (int m2 = 0; m2 < 4; ++m2) {
        #pragma unroll
        for (int rr = 0; rr < 4; ++rr) {
            int row = m2 * 16 + qq * 4 + rr;
            float gg = accG[m2][rr], u = accU[m2][rr];
            float p = gg / (1.f + __expf(-gg)) * u;
            P[(size_t)(e * CAP + m0 + row) * F_DIM + bf + wv * 16 + jj] = (f16)p;
        }
    }
}

// ---------------------------------------------------------------------------
// K3b (R4 exact): R1 geometry (64 rows x 128 h-cols, 256 thr, 8192 blocks,
// wave = 64m x 2 n-tiles) + verified XOR-swizzled unpadded Ps[64][64].
// Plain f16 stores to slot-indexed Y[E*CAP][H]; combine applies weights.
// ---------------------------------------------------------------------------
__global__ __launch_bounds__(256) void gemm2_kernel(
    const f16* __restrict__ P, const f16* __restrict__ w2p,
    const int* __restrict__ counts, f16* __restrict__ Y)
{
    const int id = blockIdx.x;
    const int x7 = id & 7, r = id >> 3;
    const int ht = r & 7, mt = (r >> 3) & 15, eh = r >> 7;
    const int e = x7 + 8 * eh;
    const int cnt = counts[e];
    const int m0 = mt * 64;
    if (m0 >= cnt) return;
    const int h0 = ht * 128;

    __shared__ f16 Ps[2][64][64];

    const int tid = threadIdx.x;
    const int lane = tid & 63, wv = tid >> 6;
    const int jj = lane & 15, qq = lane >> 4;
    const int sr = tid >> 3, sc = (tid & 7) * 8;
    const int swz_w = ((tid & 7) ^ (sr & 7)) * 8;
    const int x8 = jj & 7;
    const int s0 = (qq ^ x8) * 8;
    const int s1 = ((qq + 4) ^ x8) * 8;

    const size_t pbase = (size_t)(e * CAP + m0) * F_DIM;
    const f16* wA = w2p + ((size_t)(e * 64 + ht * 8 + wv) * 16) * 512 + lane * 8;
    const f16* wB = w2p + ((size_t)(e * 64 + ht * 8 + wv + 4) * 16) * 512 + lane * 8;

    f32x4 accA[4], accB[4];
    #pragma unroll
    for (int i = 0; i < 4; ++i) {
        accA[i] = (f32x4){0.f, 0.f, 0.f, 0.f};
        accB[i] = (f32x4){0.f, 0.f, 0.f, 0.f};
    }

    {
        f16x8 a = *(const f16x8*)(P + pbase + (size_t)sr * F_DIM + sc);
        f16x8 b = *(const f16x8*)(P + pbase + (size_t)(sr + 32) * F_DIM + sc);
        *(f16x8*)&Ps[0][sr][swz_w]      = a;
        *(f16x8*)&Ps[0][sr + 32][swz_w] = b;
    }
    f16x8 cA0 = *(const f16x8*)(wA);
    f16x8 cA1 = *(const f16x8*)(wA + 512);
    f16x8 cB0 = *(const f16x8*)(wB);
    f16x8 cB1 = *(const f16x8*)(wB + 512);

    #pragma unroll
    for (int it = 0; it < 8; ++it) {
        const int k0 = it * 64;
        __syncthreads();
        f16x8 pn0, pn1, nA0, nA1, nB0, nB1;
        if (it < 7) {
            pn0 = *(const f16x8*)(P + pbase + (size_t)sr * F_DIM + k0 + 64 + sc);
            pn1 = *(const f16x8*)(P + pbase + (size_t)(sr + 32) * F_DIM + k0 + 64 + sc);
            size_t kg = (size_t)(2 * it + 2) * 512;
            nA0 = *(const f16x8*)(wA + kg);
            nA1 = *(const f16x8*)(wA + kg + 512);
            nB0 = *(const f16x8*)(wB + kg);
            nB1 = *(const f16x8*)(wB + kg + 512);
        }
        const int buf = it & 1;
        #pragma unroll
        for (int m2 = 0; m2 < 4; ++m2) {
            f16x8 a0 = *(const f16x8*)&Ps[buf][m2 * 16 + jj][s0];
            f16x8 a1 = *(const f16x8*)&Ps[buf][m2 * 16 + jj][s1];
            accA[m2] = MFMA16(a0, cA0, accA[m2]);
            accB[m2] = MFMA16(a0, cB0, accB[m2]);
            accA[m2] = MFMA16(a1, cA1, accA[m2]);
            accB[m2] = MFMA16(a1, cB1, accB[m2]);
        }
        if (it < 7) {
            *(f16x8*)&Ps[buf ^ 1][sr][swz_w]      = pn0;
            *(f16x8*)&Ps[buf ^ 1][sr + 32][swz_w] = pn1;
            cA0 = nA0; cA1 = nA1; cB0 = nB0; cB1 = nB1;
        }
    }
    // plain f16 stores; rows >= cnt write dead slots never referenced by combine
    f16* yb = Y + (size_t)(e * CAP + m0) * H_DIM + h0 + wv * 16 + jj;
    #pragma unroll
    for (int m2 = 0; m2 < 4; ++m2) {
        #pragma unroll
        for (int rr = 0; rr < 4; ++rr) {
            int row = m2 * 16 + qq * 4 + rr;
            yb[(size_t)row * H_DIM]      = (f16)accA[m2][rr];
            yb[(size_t)row * H_DIM + 64] = (f16)accB[m2][rr];
        }
    }
}

// ---------------------------------------------------------------------------
// K4: combine — out[t] = sum_k wgt[t,k] * Y[slot[t,k]]. Streaming gather;
// fully overwrites out (no memset needed). 2 tokens/block, 128 thr/token.
// ---------------------------------------------------------------------------
__global__ __launch_bounds__(256) void combine_kernel(
    const f16* __restrict__ Y, const int* __restrict__ slotA,
    const float* __restrict__ wgtA, float* __restrict__ out)
{
    const int tid = threadIdx.x;
    const int t  = blockIdx.x * 2 + (tid >> 7);
    const int hc = (tid & 127) * 8;
    float acc[8] = {0.f, 0.f, 0.f, 0.f, 0.f, 0.f, 0.f, 0.f};
    const int base = t * TOPK;
    #pragma unroll
    for (int k = 0; k < 8; ++k) {
        int s   = slotA[base + k];      // wave-uniform
        float w = wgtA[base + k];
        if (s >= 0) {
            f16x8 y = *(const f16x8*)(Y + (size_t)s * H_DIM + hc);
            #pragma unroll
            for (int j = 0; j < 8; ++j) acc[j] += w * (float)y[j];
        }
    }
    float4 o0 = {acc[0], acc[1], acc[2], acc[3]};
    float4 o1 = {acc[4], acc[5], acc[6], acc[7]};
    *(float4*)(out + (size_t)t * H_DIM + hc)     = o0;
    *(float4*)(out + (size_t)t * H_DIM + hc + 4) = o1;
}

extern "C" void kernel_launch(void* const* d_in, const int* in_sizes, int n_in,
                              void* d_out, int out_size, void* d_ws, size_t ws_size,
                              hipStream_t stream) {
    const float* x  = (const float*)d_in[0];   // [T,H]
    const float* wg = (const float*)d_in[1];   // [H,E]
    const float* w1 = (const float*)d_in[2];   // [E,H,F]
    const float* w3 = (const float*)d_in[3];   // [E,H,F]
    const float* w2 = (const float*)d_in[4];   // [E,F,H]

    float* out    = (float*)d_out;
    float* logits = out + (size_t)T_TOK * H_DIM;

    char* ws = (char*)d_ws;
    int*   sel      = (int*)  (ws);
    float* wgtA     = (float*)(ws + (128 << 10));
    int*   tok_list = (int*)  (ws + (256 << 10));
    int*   slotA    = (int*)  (ws + (512 << 10));
    int*   counts   = (int*)  (ws + (768 << 10));
    f16*   xh       = (f16*)  (ws + (size_t)(1 << 20));     // 8 MB
    f16*   P        = (f16*)  (ws + (size_t)(9 << 20));     // 64 MB
    f16*   w1p      = (f16*)  (ws + (size_t)(73 << 20));    // 64 MB
    f16*   w3p      = (f16*)  (ws + (size_t)(137 << 20));   // 64 MB
    f16*   w2p      = (f16*)  (ws + (size_t)(201 << 20));   // 64 MB (end 265 MB)
    // Y aliases w1p+w3p (dead after gemm1; same-stream ordering makes this safe)
    f16*   Y        = (f16*)  (ws + (size_t)(73 << 20));    // 128 MB [E*CAP, H]

    pack_w_kernel<<<8192, 256, 0, stream>>>(w1, w1p, 512,  32, 5, 4);  // 32768 pairs
    pack_w_kernel<<<8192, 256, 0, stream>>>(w3, w3p, 512,  32, 5, 4);
    pack_w_kernel<<<8192, 256, 0, stream>>>(w2, w2p, 1024, 16, 4, 5);
    router_kernel<<<T_TOK / 4, 256, 0, stream>>>(x, wg, logits, sel, wgtA, xh);
    build_lists_kernel<<<E_EXP, 256, 0, stream>>>(sel, tok_list, slotA, counts);
    gemm1_kernel<<<8192, 256, 0, stream>>>(xh, w1p, w3p, tok_list, counts, P);
    gemm2_kernel<<<8192, 256, 0, stream>>>(P, w2p, counts, Y);
    combine_kernel<<<T_TOK / 2, 256, 0, stream>>>(Y, slotA, wgtA, out);
}